// Round 1
// baseline (23209.904 us; speedup 1.0000x reference)
//
#include <hip/hip_runtime.h>
#include <math.h>

#define S_LEN 4096
#define L_CH  12
#define CE    64
#define CHD   128
#define WE    256
#define HD    512
#define TAGS  64
#define GW    (4*HD)      // 2048
#define XDIM  (CHD+WE)    // 384
#define NBLK  32          // word-LSTM blocks

// ws layout (float offsets)
#define WS_GX    0
#define WS_CREP  (WS_GX   + (size_t)S_LEN*GW)    // 8,388,608
#define WS_OUTS  (WS_CREP + (size_t)S_LEN*CHD)   // +524,288
#define WS_HBUF  (WS_OUTS + (size_t)S_LEN*HD)    // +2,097,152
#define WS_FLAGS (WS_HBUF + 2*HD)                // +1024 (ints)

static __device__ __forceinline__ float sigf(float x) {
    return 1.0f / (1.0f + __expf(-x));
}

// ---------------------------------------------------------------------------
// K_init: h_buf[0] = hx0, h_buf[1] = 0, flags = 0   (re-run every call: ws is
// re-poisoned to 0xAA before each timed launch)
// ---------------------------------------------------------------------------
__global__ void k_init(const float* __restrict__ hx0, float* __restrict__ hbuf,
                       int* __restrict__ flags) {
    int t = threadIdx.x;
    if (t < HD) { hbuf[t] = hx0[t]; hbuf[HD + t] = 0.0f; }
    if (t < NBLK) flags[t] = 0;
}

// ---------------------------------------------------------------------------
// K1: char LSTM. 256 blocks x 256 threads; block owns 16 words, runs 12 steps.
// thread: wg=tid&3 (4 words), rg=tid>>2 (8 gate rows); weights streamed from
// L1/L2 (dedup across the 4 word-group lanes), x/h operands from padded LDS.
// ---------------------------------------------------------------------------
__global__ __launch_bounds__(256) void k_char_lstm(
    const int* __restrict__ c_seq, const float* __restrict__ char_emb,
    const float* __restrict__ c_hx0, const float* __restrict__ c_cx0,
    const float* __restrict__ Wih1, const float* __restrict__ Whh1,
    const float* __restrict__ bih1, const float* __restrict__ bhh1,
    float* __restrict__ char_rep)
{
    __shared__ float xs[16][CE + 4];    // stride 68 (odd quads -> 2-way max)
    __shared__ float hs[16][CHD + 4];   // stride 132
    __shared__ float cs[16][CHD + 4];
    __shared__ float gs[16][4*CHD + 4]; // stride 516
    const int tid = threadIdx.x;
    const int w0  = blockIdx.x * 16;

    for (int u = tid; u < 16*CHD; u += 256) {
        int w = u >> 7, k = u & (CHD-1);
        hs[w][k] = c_hx0[k];
        cs[w][k] = c_cx0[k];
    }
    __syncthreads();

    const int wg = tid & 3;        // word group: words wg*4 .. wg*4+3
    const int rg = tid >> 2;       // row group: rows rg*8 .. rg*8+7
    const int uw = tid >> 4;       // update: word
    const int uj = (tid & 15) * 8; // update: 8 h-units

    for (int t = 0; t < L_CH; ++t) {
        // stage x_t
        {
            int w = tid >> 4, k4 = (tid & 15) * 4;
            int ci = c_seq[(w0 + w) * L_CH + t];
            float4 v = *(const float4*)(char_emb + (size_t)ci * CE + k4);
            *(float4*)&xs[w][k4] = v;
        }
        __syncthreads();

        float acc[8][4];
        #pragma unroll
        for (int i = 0; i < 8; ++i)
            #pragma unroll
            for (int j = 0; j < 4; ++j) acc[i][j] = 0.0f;

        // x @ Wih1^T
        for (int kc = 0; kc < CE/4; ++kc) {
            int k = kc * 4;
            float4 xv[4];
            #pragma unroll
            for (int j = 0; j < 4; ++j) xv[j] = *(const float4*)&xs[wg*4 + j][k];
            #pragma unroll
            for (int i = 0; i < 8; ++i) {
                int r = rg*8 + i;
                float4 wv = *(const float4*)(Wih1 + (size_t)r*CE + k);
                #pragma unroll
                for (int j = 0; j < 4; ++j)
                    acc[i][j] += wv.x*xv[j].x + wv.y*xv[j].y + wv.z*xv[j].z + wv.w*xv[j].w;
            }
        }
        // h @ Whh1^T
        for (int kc = 0; kc < CHD/4; ++kc) {
            int k = kc * 4;
            float4 hv[4];
            #pragma unroll
            for (int j = 0; j < 4; ++j) hv[j] = *(const float4*)&hs[wg*4 + j][k];
            #pragma unroll
            for (int i = 0; i < 8; ++i) {
                int r = rg*8 + i;
                float4 wv = *(const float4*)(Whh1 + (size_t)r*CHD + k);
                #pragma unroll
                for (int j = 0; j < 4; ++j)
                    acc[i][j] += wv.x*hv[j].x + wv.y*hv[j].y + wv.z*hv[j].z + wv.w*hv[j].w;
            }
        }
        #pragma unroll
        for (int i = 0; i < 8; ++i) {
            int r = rg*8 + i;
            float b = bih1[r] + bhh1[r];
            #pragma unroll
            for (int j = 0; j < 4; ++j) gs[wg*4 + j][r] = acc[i][j] + b;
        }
        __syncthreads();

        // elementwise update: 8 units per thread (i,f,g,o gate order)
        #pragma unroll
        for (int i = 0; i < 8; ++i) {
            int j = uj + i;
            float gi = gs[uw][j];
            float gf = gs[uw][CHD + j];
            float gg = gs[uw][2*CHD + j];
            float go = gs[uw][3*CHD + j];
            float c = sigf(gf)*cs[uw][j] + sigf(gi)*tanhf(gg);
            cs[uw][j] = c;
            hs[uw][j] = sigf(go)*tanhf(c);
        }
        __syncthreads();
    }
    #pragma unroll
    for (int i4 = 0; i4 < 2; ++i4) {
        float4 v;
        v.x = hs[uw][uj + i4*4 + 0]; v.y = hs[uw][uj + i4*4 + 1];
        v.z = hs[uw][uj + i4*4 + 2]; v.w = hs[uw][uj + i4*4 + 3];
        *(float4*)(char_rep + (size_t)(w0 + uw)*CHD + uj + i4*4) = v;
    }
}

// ---------------------------------------------------------------------------
// K2: Gx[t][2048] = concat(char_rep, wv)[t] @ Wih2^T + (bih2+bhh2)
// grid (256 word-tiles, 4 gate slices of 512)
// ---------------------------------------------------------------------------
__global__ __launch_bounds__(256) void k_gx(
    const int* __restrict__ w_seq, const float* __restrict__ word_emb,
    const float* __restrict__ char_rep,
    const float* __restrict__ Wih2, const float* __restrict__ bih2,
    const float* __restrict__ bhh2, float* __restrict__ Gx)
{
    __shared__ float xs[16][XDIM + 4];  // stride 388
    const int tid = threadIdx.x;
    const int w0  = blockIdx.x * 16;
    const int slice = blockIdx.y;       // 0..3

    {
        int w = tid >> 4, seg = tid & 15;
        int wsq = w_seq[w0 + w];
        #pragma unroll
        for (int i4 = 0; i4 < 6; ++i4) {
            int k = seg*24 + i4*4;
            float4 v;
            if (k < CHD) v = *(const float4*)(char_rep + (size_t)(w0+w)*CHD + k);
            else         v = *(const float4*)(word_emb + (size_t)wsq*WE + (k - CHD));
            *(float4*)&xs[w][k] = v;
        }
    }
    __syncthreads();

    const int wg = tid & 3, rg = tid >> 2;
    float acc[8][4];
    #pragma unroll
    for (int i = 0; i < 8; ++i)
        #pragma unroll
        for (int j = 0; j < 4; ++j) acc[i][j] = 0.0f;

    for (int kc = 0; kc < XDIM/4; ++kc) {
        int k = kc * 4;
        float4 xv[4];
        #pragma unroll
        for (int j = 0; j < 4; ++j) xv[j] = *(const float4*)&xs[wg*4 + j][k];
        #pragma unroll
        for (int i = 0; i < 8; ++i) {
            int r = slice*512 + rg*8 + i;
            float4 wv = *(const float4*)(Wih2 + (size_t)r*XDIM + k);
            #pragma unroll
            for (int j = 0; j < 4; ++j)
                acc[i][j] += wv.x*xv[j].x + wv.y*xv[j].y + wv.z*xv[j].z + wv.w*xv[j].w;
        }
    }
    #pragma unroll
    for (int i = 0; i < 8; ++i) {
        int r = slice*512 + rg*8 + i;
        float b = bih2[r] + bhh2[r];
        #pragma unroll
        for (int j = 0; j < 4; ++j)
            Gx[(size_t)(w0 + wg*4 + j)*GW + r] = acc[i][j] + b;
    }
}

// ---------------------------------------------------------------------------
// K3: sequential word LSTM. 32 persistent blocks x 256 threads.
// Block b owns h[b*16 .. b*16+15]; thread (j=tid&15, s=tid>>4) holds the
// 4-gate x 32-k Whh2 slice in VGPRs. Cross-block handoff: double-buffered
// h[2][512] + per-block flags with agent-scope atomics. Each thread spins only
// on the 2 producer flags covering its k-slice; the block barrier closes the
// skew (<=1 step) so the 2-deep ring is race-free.
// ---------------------------------------------------------------------------
__global__ __launch_bounds__(256) void k_word_lstm(
    const float* __restrict__ Gx, const float* __restrict__ Whh2,
    const float* __restrict__ cx0, float* __restrict__ hbuf,
    int* __restrict__ flags, float* __restrict__ outs)
{
    __shared__ float part[2][4][16][16];   // [parity][gate][s][j]
    const int tid = threadIdx.x;
    const int b   = blockIdx.x;
    const int hb  = b * 16;
    const int j   = tid & 15;
    const int s   = tid >> 4;      // 0..15
    const int ks  = s * 32;
    const int fa  = 2 * s;         // flags guarding h[ks..ks+31]

    // Whh2 slice -> registers: rows q*HD + hb + j, cols ks..ks+31
    float wreg[4][32];
    #pragma unroll
    for (int q = 0; q < 4; ++q) {
        const float* wr = Whh2 + (size_t)(q*HD + hb + j)*HD + ks;
        #pragma unroll
        for (int m4 = 0; m4 < 8; ++m4) {
            float4 v = *(const float4*)(wr + m4*4);
            wreg[q][m4*4+0] = v.x; wreg[q][m4*4+1] = v.y;
            wreg[q][m4*4+2] = v.z; wreg[q][m4*4+3] = v.w;
        }
    }
    float creg = 0.0f;
    if (tid < 16) creg = cx0[hb + j];

    for (int t = 0; t < S_LEN; ++t) {
        // prefetch this step's input gates (stable data, no ordering needed)
        float gx0 = 0.f, gx1 = 0.f, gx2 = 0.f, gx3 = 0.f;
        if (tid < 16) {
            const float* gp = Gx + (size_t)t*GW + hb + j;
            gx0 = gp[0]; gx1 = gp[HD]; gx2 = gp[2*HD]; gx3 = gp[3*HD];
        }
        // wait for the two blocks that produce our h k-slice
        int v = __hip_atomic_load(&flags[fa], __ATOMIC_RELAXED, __HIP_MEMORY_SCOPE_AGENT);
        while (v < t) { __builtin_amdgcn_s_sleep(2);
            v = __hip_atomic_load(&flags[fa], __ATOMIC_RELAXED, __HIP_MEMORY_SCOPE_AGENT); }
        v = __hip_atomic_load(&flags[fa+1], __ATOMIC_RELAXED, __HIP_MEMORY_SCOPE_AGENT);
        while (v < t) { __builtin_amdgcn_s_sleep(2);
            v = __hip_atomic_load(&flags[fa+1], __ATOMIC_RELAXED, __HIP_MEMORY_SCOPE_AGENT); }
        __threadfence();

        // load h slice (cache-bypassing atomics -> always fresh)
        float* hsrc = hbuf + (size_t)(t & 1)*HD + ks;
        float hv[32];
        #pragma unroll
        for (int m = 0; m < 32; ++m)
            hv[m] = __hip_atomic_load(hsrc + m, __ATOMIC_RELAXED, __HIP_MEMORY_SCOPE_AGENT);

        float a0 = 0.f, a1 = 0.f, a2 = 0.f, a3 = 0.f;
        #pragma unroll
        for (int m = 0; m < 32; ++m) {
            a0 += wreg[0][m] * hv[m];
            a1 += wreg[1][m] * hv[m];
            a2 += wreg[2][m] * hv[m];
            a3 += wreg[3][m] * hv[m];
        }
        const int par = t & 1;
        part[par][0][s][j] = a0;
        part[par][1][s][j] = a1;
        part[par][2][s][j] = a2;
        part[par][3][s][j] = a3;
        __syncthreads();

        if (tid < 16) {
            float g0 = gx0, g1 = gx1, g2 = gx2, g3 = gx3;
            #pragma unroll
            for (int ss = 0; ss < 16; ++ss) {
                g0 += part[par][0][ss][j];
                g1 += part[par][1][ss][j];
                g2 += part[par][2][ss][j];
                g3 += part[par][3][ss][j];
            }
            float c  = sigf(g1)*creg + sigf(g0)*tanhf(g2);
            creg = c;
            float hn = sigf(g3)*tanhf(c);
            outs[(size_t)t*HD + hb + j] = hn;
            __hip_atomic_store(hbuf + (size_t)((t+1) & 1)*HD + hb + j, hn,
                               __ATOMIC_RELAXED, __HIP_MEMORY_SCOPE_AGENT);
            __threadfence();
            if (tid == 0)
                __hip_atomic_store(&flags[b], t + 1,
                                   __ATOMIC_RELEASE, __HIP_MEMORY_SCOPE_AGENT);
        }
    }
}

// ---------------------------------------------------------------------------
// K4: tag projection + log_softmax. 256 blocks x 256 threads, 16 words each.
// ---------------------------------------------------------------------------
__global__ __launch_bounds__(256) void k_out(
    const float* __restrict__ outs, const float* __restrict__ W_out,
    const float* __restrict__ b_out, float* __restrict__ out)
{
    __shared__ float hh[16][HD + 4];   // stride 516
    __shared__ float ts[16][TAGS + 4]; // stride 68
    __shared__ float lse[16];
    const int tid = threadIdx.x;
    const int w0  = blockIdx.x * 16;

    {
        int w = tid >> 4, k0 = (tid & 15) * 32;
        #pragma unroll
        for (int i4 = 0; i4 < 8; ++i4)
            *(float4*)&hh[w][k0 + i4*4] =
                *(const float4*)(outs + (size_t)(w0+w)*HD + k0 + i4*4);
    }
    __syncthreads();

    const int tag = tid & 63;
    const int wg  = tid >> 6;  // 0..3 -> words wg*4..wg*4+3
    float a0 = 0.f, a1 = 0.f, a2 = 0.f, a3 = 0.f;
    for (int kc = 0; kc < HD/4; ++kc) {
        int k = kc * 4;
        float4 wv = *(const float4*)(W_out + (size_t)tag*HD + k);
        float4 x0 = *(const float4*)&hh[wg*4+0][k];
        float4 x1 = *(const float4*)&hh[wg*4+1][k];
        float4 x2 = *(const float4*)&hh[wg*4+2][k];
        float4 x3 = *(const float4*)&hh[wg*4+3][k];
        a0 += wv.x*x0.x + wv.y*x0.y + wv.z*x0.z + wv.w*x0.w;
        a1 += wv.x*x1.x + wv.y*x1.y + wv.z*x1.z + wv.w*x1.w;
        a2 += wv.x*x2.x + wv.y*x2.y + wv.z*x2.z + wv.w*x2.w;
        a3 += wv.x*x3.x + wv.y*x3.y + wv.z*x3.z + wv.w*x3.w;
    }
    float bo = b_out[tag];
    ts[wg*4+0][tag] = a0 + bo;
    ts[wg*4+1][tag] = a1 + bo;
    ts[wg*4+2][tag] = a2 + bo;
    ts[wg*4+3][tag] = a3 + bo;
    __syncthreads();

    if (tid < 16) {
        float m = -1e30f;
        for (int q = 0; q < TAGS; ++q) m = fmaxf(m, ts[tid][q]);
        float ssum = 0.0f;
        for (int q = 0; q < TAGS; ++q) ssum += __expf(ts[tid][q] - m);
        lse[tid] = m + __logf(ssum);
    }
    __syncthreads();

    #pragma unroll
    for (int jj = 0; jj < 4; ++jj)
        out[(size_t)(w0 + wg*4 + jj)*TAGS + tag] = ts[wg*4+jj][tag] - lse[wg*4+jj];
}

// ---------------------------------------------------------------------------
extern "C" void kernel_launch(void* const* d_in, const int* in_sizes, int n_in,
                              void* d_out, int out_size, void* d_ws, size_t ws_size,
                              hipStream_t stream) {
    (void)in_sizes; (void)n_in; (void)out_size; (void)ws_size;
    const int*   w_seq    = (const int*)  d_in[0];
    const int*   c_seq    = (const int*)  d_in[1];
    const float* char_emb = (const float*)d_in[2];
    const float* word_emb = (const float*)d_in[3];
    const float* c_hx0    = (const float*)d_in[4];
    const float* c_cx0    = (const float*)d_in[5];
    const float* hx0      = (const float*)d_in[6];
    const float* cx0      = (const float*)d_in[7];
    const float* Wih1     = (const float*)d_in[8];
    const float* Whh1     = (const float*)d_in[9];
    const float* bih1     = (const float*)d_in[10];
    const float* bhh1     = (const float*)d_in[11];
    const float* Wih2     = (const float*)d_in[12];
    const float* Whh2     = (const float*)d_in[13];
    const float* bih2     = (const float*)d_in[14];
    const float* bhh2     = (const float*)d_in[15];
    const float* W_out    = (const float*)d_in[16];
    const float* b_out    = (const float*)d_in[17];

    float* ws    = (float*)d_ws;
    float* Gx    = ws + WS_GX;
    float* crep  = ws + WS_CREP;
    float* outs  = ws + WS_OUTS;
    float* hbuf  = ws + WS_HBUF;
    int*   flags = (int*)(ws + WS_FLAGS);

    hipLaunchKernelGGL(k_init, dim3(1), dim3(512), 0, stream, hx0, hbuf, flags);
    hipLaunchKernelGGL(k_char_lstm, dim3(256), dim3(256), 0, stream,
                       c_seq, char_emb, c_hx0, c_cx0, Wih1, Whh1, bih1, bhh1, crep);
    hipLaunchKernelGGL(k_gx, dim3(256, 4), dim3(256), 0, stream,
                       w_seq, word_emb, crep, Wih2, bih2, bhh2, Gx);
    hipLaunchKernelGGL(k_word_lstm, dim3(NBLK), dim3(256), 0, stream,
                       Gx, Whh2, cx0, hbuf, flags, outs);
    hipLaunchKernelGGL(k_out, dim3(256), dim3(256), 0, stream,
                       outs, W_out, b_out, (float*)d_out);
}

// Round 2
// 21741.447 us; speedup vs baseline: 1.0675x; 1.0675x over previous
//
#include <hip/hip_runtime.h>
#include <math.h>

#define S_LEN 4096
#define L_CH  12
#define CE    64
#define CHD   128
#define WE    256
#define HD    512
#define TAGS  64
#define GW    (4*HD)      // 2048
#define XDIM  (CHD+WE)    // 384
#define NBLK  32          // word-LSTM blocks

// ws layout (float offsets)
#define WS_GX    0
#define WS_CREP  (WS_GX   + (size_t)S_LEN*GW)      // 8,388,608 floats
#define WS_HEXT  (WS_CREP + (size_t)S_LEN*CHD)     // +524,288
// hext: (S_LEN+1) rows x HD. Row r = h_{r-1} + 2.0 (row 0 = hx0+2).
// Rows 1..S_LEN double as `outs` (+2 bias) for k_out.

static __device__ __forceinline__ float sigf(float x) {
    return 1.0f / (1.0f + __expf(-x));
}
// overflow-safe tanh via exp2-based __expf: 1 - 2/(e^{2x}+1)
static __device__ __forceinline__ float tanhfast(float x) {
    return 1.0f - 2.0f / (__expf(2.0f * x) + 1.0f);
}

// ---------------------------------------------------------------------------
// K_init: hext row 0 = hx0 + 2, rows 1..S_LEN = 0. (ws poisoned to 0xAA each
// call; poison is negative as float so it would read "not ready", but we zero
// explicitly rather than rely on poison.)
// ---------------------------------------------------------------------------
__global__ __launch_bounds__(256) void k_init(const float* __restrict__ hx0,
                                              float* __restrict__ hext) {
    size_t i = ((size_t)blockIdx.x * 256 + threadIdx.x) * 4;
    if (i >= (size_t)(S_LEN + 1) * HD) return;
    float4 v;
    if (i < HD) {
        v.x = hx0[i+0] + 2.0f; v.y = hx0[i+1] + 2.0f;
        v.z = hx0[i+2] + 2.0f; v.w = hx0[i+3] + 2.0f;
    } else {
        v = make_float4(0.f, 0.f, 0.f, 0.f);
    }
    *(float4*)(hext + i) = v;
}

// ---------------------------------------------------------------------------
// K1: char LSTM. 256 blocks x 256 threads; block owns 16 words, runs 12 steps.
// ---------------------------------------------------------------------------
__global__ __launch_bounds__(256) void k_char_lstm(
    const int* __restrict__ c_seq, const float* __restrict__ char_emb,
    const float* __restrict__ c_hx0, const float* __restrict__ c_cx0,
    const float* __restrict__ Wih1, const float* __restrict__ Whh1,
    const float* __restrict__ bih1, const float* __restrict__ bhh1,
    float* __restrict__ char_rep)
{
    __shared__ float xs[16][CE + 4];
    __shared__ float hs[16][CHD + 4];
    __shared__ float cs[16][CHD + 4];
    __shared__ float gs[16][4*CHD + 4];
    const int tid = threadIdx.x;
    const int w0  = blockIdx.x * 16;

    for (int u = tid; u < 16*CHD; u += 256) {
        int w = u >> 7, k = u & (CHD-1);
        hs[w][k] = c_hx0[k];
        cs[w][k] = c_cx0[k];
    }
    __syncthreads();

    const int wg = tid & 3;
    const int rg = tid >> 2;
    const int uw = tid >> 4;
    const int uj = (tid & 15) * 8;

    for (int t = 0; t < L_CH; ++t) {
        {
            int w = tid >> 4, k4 = (tid & 15) * 4;
            int ci = c_seq[(w0 + w) * L_CH + t];
            float4 v = *(const float4*)(char_emb + (size_t)ci * CE + k4);
            *(float4*)&xs[w][k4] = v;
        }
        __syncthreads();

        float acc[8][4];
        #pragma unroll
        for (int i = 0; i < 8; ++i)
            #pragma unroll
            for (int j = 0; j < 4; ++j) acc[i][j] = 0.0f;

        for (int kc = 0; kc < CE/4; ++kc) {
            int k = kc * 4;
            float4 xv[4];
            #pragma unroll
            for (int j = 0; j < 4; ++j) xv[j] = *(const float4*)&xs[wg*4 + j][k];
            #pragma unroll
            for (int i = 0; i < 8; ++i) {
                int r = rg*8 + i;
                float4 wv = *(const float4*)(Wih1 + (size_t)r*CE + k);
                #pragma unroll
                for (int j = 0; j < 4; ++j)
                    acc[i][j] += wv.x*xv[j].x + wv.y*xv[j].y + wv.z*xv[j].z + wv.w*xv[j].w;
            }
        }
        for (int kc = 0; kc < CHD/4; ++kc) {
            int k = kc * 4;
            float4 hv[4];
            #pragma unroll
            for (int j = 0; j < 4; ++j) hv[j] = *(const float4*)&hs[wg*4 + j][k];
            #pragma unroll
            for (int i = 0; i < 8; ++i) {
                int r = rg*8 + i;
                float4 wv = *(const float4*)(Whh1 + (size_t)r*CHD + k);
                #pragma unroll
                for (int j = 0; j < 4; ++j)
                    acc[i][j] += wv.x*hv[j].x + wv.y*hv[j].y + wv.z*hv[j].z + wv.w*hv[j].w;
            }
        }
        #pragma unroll
        for (int i = 0; i < 8; ++i) {
            int r = rg*8 + i;
            float b = bih1[r] + bhh1[r];
            #pragma unroll
            for (int j = 0; j < 4; ++j) gs[wg*4 + j][r] = acc[i][j] + b;
        }
        __syncthreads();

        #pragma unroll
        for (int i = 0; i < 8; ++i) {
            int j = uj + i;
            float gi = gs[uw][j];
            float gf = gs[uw][CHD + j];
            float gg = gs[uw][2*CHD + j];
            float go = gs[uw][3*CHD + j];
            float c = sigf(gf)*cs[uw][j] + sigf(gi)*tanhfast(gg);
            cs[uw][j] = c;
            hs[uw][j] = sigf(go)*tanhfast(c);
        }
        __syncthreads();
    }
    #pragma unroll
    for (int i4 = 0; i4 < 2; ++i4) {
        float4 v;
        v.x = hs[uw][uj + i4*4 + 0]; v.y = hs[uw][uj + i4*4 + 1];
        v.z = hs[uw][uj + i4*4 + 2]; v.w = hs[uw][uj + i4*4 + 3];
        *(float4*)(char_rep + (size_t)(w0 + uw)*CHD + uj + i4*4) = v;
    }
}

// ---------------------------------------------------------------------------
// K2: Gx[t][2048] = concat(char_rep, wv)[t] @ Wih2^T + (bih2+bhh2)
// ---------------------------------------------------------------------------
__global__ __launch_bounds__(256) void k_gx(
    const int* __restrict__ w_seq, const float* __restrict__ word_emb,
    const float* __restrict__ char_rep,
    const float* __restrict__ Wih2, const float* __restrict__ bih2,
    const float* __restrict__ bhh2, float* __restrict__ Gx)
{
    __shared__ float xs[16][XDIM + 4];
    const int tid = threadIdx.x;
    const int w0  = blockIdx.x * 16;
    const int slice = blockIdx.y;

    {
        int w = tid >> 4, seg = tid & 15;
        int wsq = w_seq[w0 + w];
        #pragma unroll
        for (int i4 = 0; i4 < 6; ++i4) {
            int k = seg*24 + i4*4;
            float4 v;
            if (k < CHD) v = *(const float4*)(char_rep + (size_t)(w0+w)*CHD + k);
            else         v = *(const float4*)(word_emb + (size_t)wsq*WE + (k - CHD));
            *(float4*)&xs[w][k] = v;
        }
    }
    __syncthreads();

    const int wg = tid & 3, rg = tid >> 2;
    float acc[8][4];
    #pragma unroll
    for (int i = 0; i < 8; ++i)
        #pragma unroll
        for (int j = 0; j < 4; ++j) acc[i][j] = 0.0f;

    for (int kc = 0; kc < XDIM/4; ++kc) {
        int k = kc * 4;
        float4 xv[4];
        #pragma unroll
        for (int j = 0; j < 4; ++j) xv[j] = *(const float4*)&xs[wg*4 + j][k];
        #pragma unroll
        for (int i = 0; i < 8; ++i) {
            int r = slice*512 + rg*8 + i;
            float4 wv = *(const float4*)(Wih2 + (size_t)r*XDIM + k);
            #pragma unroll
            for (int j = 0; j < 4; ++j)
                acc[i][j] += wv.x*xv[j].x + wv.y*xv[j].y + wv.z*xv[j].z + wv.w*xv[j].w;
        }
    }
    #pragma unroll
    for (int i = 0; i < 8; ++i) {
        int r = slice*512 + rg*8 + i;
        float b = bih2[r] + bhh2[r];
        #pragma unroll
        for (int j = 0; j < 4; ++j)
            Gx[(size_t)(w0 + wg*4 + j)*GW + r] = acc[i][j] + b;
    }
}

// ---------------------------------------------------------------------------
// K3: sequential word LSTM, data-as-flag protocol.
// 32 blocks x 256 threads. Wave w of block b owns outputs jo = b*16+w*4+jj
// (jj = lane&3); lane's k-slice is s = lane>>2 (32 k each). Whh2 slice held in
// VGPRs. Step t: poll hext row t (values stored as h+2, ready iff > 0.5),
// matvec, in-wave butterfly reduce over s, gate nonlinearity in s==0 lanes,
// store row t+1. No fences, no flags, no __syncthreads: rows are write-once,
// all cross-block traffic is agent-scope (MALL-coherent) relaxed atomics, and
// in-order issue per wave means h-loads follow the poll that saw readiness.
// ---------------------------------------------------------------------------
__global__ __launch_bounds__(256, 1) void k_word_lstm(
    const float* __restrict__ Gx, const float* __restrict__ Whh2,
    const float* __restrict__ cx0, float* __restrict__ hext)
{
    const int tid  = threadIdx.x;
    const int b    = blockIdx.x;
    const int hb   = b * 16;
    const int w    = tid >> 6;        // wave 0..3
    const int lane = tid & 63;
    const int jj   = lane & 3;
    const int s    = lane >> 2;       // 0..15
    const int ks   = s * 32;
    const int jo   = hb + w*4 + jj;   // output index this lane serves

    // Whh2 slice -> registers: rows q*HD + jo, cols ks..ks+31; wsum = 2*sum
    float wreg[4][32];
    float wsum[4];
    #pragma unroll
    for (int q = 0; q < 4; ++q) {
        const float* wr = Whh2 + (size_t)(q*HD + jo)*HD + ks;
        float ssum = 0.0f;
        #pragma unroll
        for (int m4 = 0; m4 < 8; ++m4) {
            float4 v = *(const float4*)(wr + m4*4);
            wreg[q][m4*4+0] = v.x; wreg[q][m4*4+1] = v.y;
            wreg[q][m4*4+2] = v.z; wreg[q][m4*4+3] = v.w;
            ssum += v.x + v.y + v.z + v.w;
        }
        wsum[q] = 2.0f * ssum;
    }
    float creg = (s == 0) ? cx0[jo] : 0.0f;

    for (int t = 0; t < S_LEN; ++t) {
        // issue Gx loads first (normal cached loads, overlap the poll)
        float gx0 = 0.f, gx1 = 0.f, gx2 = 0.f, gx3 = 0.f;
        if (s == 0) {
            const float* gp = Gx + (size_t)t*GW + jo;
            gx0 = gp[0]; gx1 = gp[HD]; gx2 = gp[2*HD]; gx3 = gp[3*HD];
        }

        const float* hsrc = hext + (size_t)t*HD + ks;
        float hv[32];
        for (;;) {
            float mn = 1e30f;
            #pragma unroll
            for (int m = 0; m < 32; ++m) {
                hv[m] = __hip_atomic_load(hsrc + m, __ATOMIC_RELAXED,
                                          __HIP_MEMORY_SCOPE_AGENT);
                mn = fminf(mn, hv[m]);
            }
            if (__all(mn > 0.5f)) break;
            __builtin_amdgcn_s_sleep(1);
        }

        // matvec on (h+2); subtract folded 2*sum(w) afterwards
        float a0 = 0.f, a1 = 0.f, a2 = 0.f, a3 = 0.f;
        #pragma unroll
        for (int m = 0; m < 32; ++m) {
            a0 += wreg[0][m] * hv[m];
            a1 += wreg[1][m] * hv[m];
            a2 += wreg[2][m] * hv[m];
            a3 += wreg[3][m] * hv[m];
        }
        a0 -= wsum[0]; a1 -= wsum[1]; a2 -= wsum[2]; a3 -= wsum[3];

        // in-wave butterfly over the s bits (lane ^ 4,8,16,32)
        #pragma unroll
        for (int off = 4; off < 64; off <<= 1) {
            a0 += __shfl_xor(a0, off, 64);
            a1 += __shfl_xor(a1, off, 64);
            a2 += __shfl_xor(a2, off, 64);
            a3 += __shfl_xor(a3, off, 64);
        }

        if (s == 0) {
            float g0 = gx0 + a0, g1 = gx1 + a1, g2 = gx2 + a2, g3 = gx3 + a3;
            float c  = sigf(g1)*creg + sigf(g0)*tanhfast(g2);
            creg = c;
            float hn = sigf(g3)*tanhfast(c);
            __hip_atomic_store(hext + (size_t)(t+1)*HD + jo, hn + 2.0f,
                               __ATOMIC_RELAXED, __HIP_MEMORY_SCOPE_AGENT);
        }
    }
}

// ---------------------------------------------------------------------------
// K4: tag projection + log_softmax. Reads hext rows 1..S_LEN, subtracting the
// +2 bias at stage time.
// ---------------------------------------------------------------------------
__global__ __launch_bounds__(256) void k_out(
    const float* __restrict__ outs_b, const float* __restrict__ W_out,
    const float* __restrict__ b_out, float* __restrict__ out)
{
    __shared__ float hh[16][HD + 4];
    __shared__ float ts[16][TAGS + 4];
    __shared__ float lse[16];
    const int tid = threadIdx.x;
    const int w0  = blockIdx.x * 16;

    {
        int w = tid >> 4, k0 = (tid & 15) * 32;
        #pragma unroll
        for (int i4 = 0; i4 < 8; ++i4) {
            float4 v = *(const float4*)(outs_b + (size_t)(w0+w)*HD + k0 + i4*4);
            int k = k0 + i4*4;
            hh[w][k+0] = v.x - 2.0f; hh[w][k+1] = v.y - 2.0f;
            hh[w][k+2] = v.z - 2.0f; hh[w][k+3] = v.w - 2.0f;
        }
    }
    __syncthreads();

    const int tag = tid & 63;
    const int wg  = tid >> 6;
    float a0 = 0.f, a1 = 0.f, a2 = 0.f, a3 = 0.f;
    for (int kc = 0; kc < HD/4; ++kc) {
        int k = kc * 4;
        float4 wv = *(const float4*)(W_out + (size_t)tag*HD + k);
        float4 x0 = *(const float4*)&hh[wg*4+0][k];
        float4 x1 = *(const float4*)&hh[wg*4+1][k];
        float4 x2 = *(const float4*)&hh[wg*4+2][k];
        float4 x3 = *(const float4*)&hh[wg*4+3][k];
        a0 += wv.x*x0.x + wv.y*x0.y + wv.z*x0.z + wv.w*x0.w;
        a1 += wv.x*x1.x + wv.y*x1.y + wv.z*x1.z + wv.w*x1.w;
        a2 += wv.x*x2.x + wv.y*x2.y + wv.z*x2.z + wv.w*x2.w;
        a3 += wv.x*x3.x + wv.y*x3.y + wv.z*x3.z + wv.w*x3.w;
    }
    float bo = b_out[tag];
    ts[wg*4+0][tag] = a0 + bo;
    ts[wg*4+1][tag] = a1 + bo;
    ts[wg*4+2][tag] = a2 + bo;
    ts[wg*4+3][tag] = a3 + bo;
    __syncthreads();

    if (tid < 16) {
        float m = -1e30f;
        for (int q = 0; q < TAGS; ++q) m = fmaxf(m, ts[tid][q]);
        float ssum = 0.0f;
        for (int q = 0; q < TAGS; ++q) ssum += __expf(ts[tid][q] - m);
        lse[tid] = m + __logf(ssum);
    }
    __syncthreads();

    #pragma unroll
    for (int jjj = 0; jjj < 4; ++jjj)
        out[(size_t)(w0 + wg*4 + jjj)*TAGS + tag] = ts[wg*4+jjj][tag] - lse[wg*4+jjj];
}

// ---------------------------------------------------------------------------
extern "C" void kernel_launch(void* const* d_in, const int* in_sizes, int n_in,
                              void* d_out, int out_size, void* d_ws, size_t ws_size,
                              hipStream_t stream) {
    (void)in_sizes; (void)n_in; (void)out_size; (void)ws_size;
    const int*   w_seq    = (const int*)  d_in[0];
    const int*   c_seq    = (const int*)  d_in[1];
    const float* char_emb = (const float*)d_in[2];
    const float* word_emb = (const float*)d_in[3];
    const float* c_hx0    = (const float*)d_in[4];
    const float* c_cx0    = (const float*)d_in[5];
    const float* hx0      = (const float*)d_in[6];
    const float* cx0      = (const float*)d_in[7];
    const float* Wih1     = (const float*)d_in[8];
    const float* Whh1     = (const float*)d_in[9];
    const float* bih1     = (const float*)d_in[10];
    const float* bhh1     = (const float*)d_in[11];
    const float* Wih2     = (const float*)d_in[12];
    const float* Whh2     = (const float*)d_in[13];
    const float* bih2     = (const float*)d_in[14];
    const float* bhh2     = (const float*)d_in[15];
    const float* W_out    = (const float*)d_in[16];
    const float* b_out    = (const float*)d_in[17];

    float* ws   = (float*)d_ws;
    float* Gx   = ws + WS_GX;
    float* crep = ws + WS_CREP;
    float* hext = ws + WS_HEXT;

    int init_blocks = (int)(((size_t)(S_LEN + 1) * HD / 4 + 255) / 256);
    hipLaunchKernelGGL(k_init, dim3(init_blocks), dim3(256), 0, stream, hx0, hext);
    hipLaunchKernelGGL(k_char_lstm, dim3(256), dim3(256), 0, stream,
                       c_seq, char_emb, c_hx0, c_cx0, Wih1, Whh1, bih1, bhh1, crep);
    hipLaunchKernelGGL(k_gx, dim3(256, 4), dim3(256), 0, stream,
                       w_seq, word_emb, crep, Wih2, bih2, bhh2, Gx);
    hipLaunchKernelGGL(k_word_lstm, dim3(NBLK), dim3(256), 0, stream,
                       Gx, Whh2, cx0, hext);
    hipLaunchKernelGGL(k_out, dim3(256), dim3(256), 0, stream,
                       hext + HD, W_out, b_out, (float*)d_out);
}

// Round 3
// 10633.247 us; speedup vs baseline: 2.1828x; 2.0447x over previous
//
#include <hip/hip_runtime.h>
#include <math.h>

#define S_LEN 4096
#define L_CH  12
#define CE    64
#define CHD   128
#define WE    256
#define HD    512
#define TAGS  64
#define GW    (4*HD)      // 2048
#define XDIM  (CHD+WE)    // 384
#define NBLK  64          // word-LSTM blocks (8 outputs each)

// ws layout (float offsets)
#define WS_GX    0
#define WS_CREP  (WS_GX   + (size_t)S_LEN*GW)      // 8,388,608 floats
#define WS_HEXT  (WS_CREP + (size_t)S_LEN*CHD)     // +524,288
// hext: (S_LEN+1) rows x HD. Row r = h_{r-1} + 2.0 (row 0 = hx0+2).
// Rows 1..S_LEN double as `outs` (+2 bias) for k_out.

typedef float v4f __attribute__((ext_vector_type(4)));

static __device__ __forceinline__ float sigf(float x) {
    return 1.0f / (1.0f + __expf(-x));
}
static __device__ __forceinline__ float tanhfast(float x) {
    return 1.0f - 2.0f / (__expf(2.0f * x) + 1.0f);
}

// ---------------------------------------------------------------------------
// K_init: hext row 0 = hx0 + 2, rows 1..S_LEN = 0. Stores bypass L1/L2
// (sc0 sc1) so no dirty L2 lines can later evict over K3's MALL-level writes.
// ---------------------------------------------------------------------------
__global__ __launch_bounds__(256) void k_init(const float* __restrict__ hx0,
                                              float* __restrict__ hext) {
    size_t i = ((size_t)blockIdx.x * 256 + threadIdx.x) * 4;
    if (i >= (size_t)(S_LEN + 1) * HD) return;
    v4f v;
    if (i < HD) {
        v.x = hx0[i+0] + 2.0f; v.y = hx0[i+1] + 2.0f;
        v.z = hx0[i+2] + 2.0f; v.w = hx0[i+3] + 2.0f;
    } else {
        v.x = 0.f; v.y = 0.f; v.z = 0.f; v.w = 0.f;
    }
    float* p = hext + i;
    asm volatile("global_store_dwordx4 %0, %1, off sc0 sc1"
                 :: "v"(p), "v"(v) : "memory");
}

// ---------------------------------------------------------------------------
// K1: char LSTM. 256 blocks x 256 threads; block owns 16 words, runs 12 steps.
// ---------------------------------------------------------------------------
__global__ __launch_bounds__(256) void k_char_lstm(
    const int* __restrict__ c_seq, const float* __restrict__ char_emb,
    const float* __restrict__ c_hx0, const float* __restrict__ c_cx0,
    const float* __restrict__ Wih1, const float* __restrict__ Whh1,
    const float* __restrict__ bih1, const float* __restrict__ bhh1,
    float* __restrict__ char_rep)
{
    __shared__ float xs[16][CE + 4];
    __shared__ float hs[16][CHD + 4];
    __shared__ float cs[16][CHD + 4];
    __shared__ float gs[16][4*CHD + 4];
    const int tid = threadIdx.x;
    const int w0  = blockIdx.x * 16;

    for (int u = tid; u < 16*CHD; u += 256) {
        int w = u >> 7, k = u & (CHD-1);
        hs[w][k] = c_hx0[k];
        cs[w][k] = c_cx0[k];
    }
    __syncthreads();

    const int wg = tid & 3;
    const int rg = tid >> 2;
    const int uw = tid >> 4;
    const int uj = (tid & 15) * 8;

    for (int t = 0; t < L_CH; ++t) {
        {
            int w = tid >> 4, k4 = (tid & 15) * 4;
            int ci = c_seq[(w0 + w) * L_CH + t];
            float4 v = *(const float4*)(char_emb + (size_t)ci * CE + k4);
            *(float4*)&xs[w][k4] = v;
        }
        __syncthreads();

        float acc[8][4];
        #pragma unroll
        for (int i = 0; i < 8; ++i)
            #pragma unroll
            for (int j = 0; j < 4; ++j) acc[i][j] = 0.0f;

        for (int kc = 0; kc < CE/4; ++kc) {
            int k = kc * 4;
            float4 xv[4];
            #pragma unroll
            for (int j = 0; j < 4; ++j) xv[j] = *(const float4*)&xs[wg*4 + j][k];
            #pragma unroll
            for (int i = 0; i < 8; ++i) {
                int r = rg*8 + i;
                float4 wv = *(const float4*)(Wih1 + (size_t)r*CE + k);
                #pragma unroll
                for (int j = 0; j < 4; ++j)
                    acc[i][j] += wv.x*xv[j].x + wv.y*xv[j].y + wv.z*xv[j].z + wv.w*xv[j].w;
            }
        }
        for (int kc = 0; kc < CHD/4; ++kc) {
            int k = kc * 4;
            float4 hv[4];
            #pragma unroll
            for (int j = 0; j < 4; ++j) hv[j] = *(const float4*)&hs[wg*4 + j][k];
            #pragma unroll
            for (int i = 0; i < 8; ++i) {
                int r = rg*8 + i;
                float4 wv = *(const float4*)(Whh1 + (size_t)r*CHD + k);
                #pragma unroll
                for (int j = 0; j < 4; ++j)
                    acc[i][j] += wv.x*hv[j].x + wv.y*hv[j].y + wv.z*hv[j].z + wv.w*hv[j].w;
            }
        }
        #pragma unroll
        for (int i = 0; i < 8; ++i) {
            int r = rg*8 + i;
            float b = bih1[r] + bhh1[r];
            #pragma unroll
            for (int j = 0; j < 4; ++j) gs[wg*4 + j][r] = acc[i][j] + b;
        }
        __syncthreads();

        #pragma unroll
        for (int i = 0; i < 8; ++i) {
            int j = uj + i;
            float gi = gs[uw][j];
            float gf = gs[uw][CHD + j];
            float gg = gs[uw][2*CHD + j];
            float go = gs[uw][3*CHD + j];
            float c = sigf(gf)*cs[uw][j] + sigf(gi)*tanhfast(gg);
            cs[uw][j] = c;
            hs[uw][j] = sigf(go)*tanhfast(c);
        }
        __syncthreads();
    }
    #pragma unroll
    for (int i4 = 0; i4 < 2; ++i4) {
        float4 v;
        v.x = hs[uw][uj + i4*4 + 0]; v.y = hs[uw][uj + i4*4 + 1];
        v.z = hs[uw][uj + i4*4 + 2]; v.w = hs[uw][uj + i4*4 + 3];
        *(float4*)(char_rep + (size_t)(w0 + uw)*CHD + uj + i4*4) = v;
    }
}

// ---------------------------------------------------------------------------
// K2: Gx[t][2048] = concat(char_rep, wv)[t] @ Wih2^T + (bih2+bhh2)
// ---------------------------------------------------------------------------
__global__ __launch_bounds__(256) void k_gx(
    const int* __restrict__ w_seq, const float* __restrict__ word_emb,
    const float* __restrict__ char_rep,
    const float* __restrict__ Wih2, const float* __restrict__ bih2,
    const float* __restrict__ bhh2, float* __restrict__ Gx)
{
    __shared__ float xs[16][XDIM + 4];
    const int tid = threadIdx.x;
    const int w0  = blockIdx.x * 16;
    const int slice = blockIdx.y;

    {
        int w = tid >> 4, seg = tid & 15;
        int wsq = w_seq[w0 + w];
        #pragma unroll
        for (int i4 = 0; i4 < 6; ++i4) {
            int k = seg*24 + i4*4;
            float4 v;
            if (k < CHD) v = *(const float4*)(char_rep + (size_t)(w0+w)*CHD + k);
            else         v = *(const float4*)(word_emb + (size_t)wsq*WE + (k - CHD));
            *(float4*)&xs[w][k] = v;
        }
    }
    __syncthreads();

    const int wg = tid & 3, rg = tid >> 2;
    float acc[8][4];
    #pragma unroll
    for (int i = 0; i < 8; ++i)
        #pragma unroll
        for (int j = 0; j < 4; ++j) acc[i][j] = 0.0f;

    for (int kc = 0; kc < XDIM/4; ++kc) {
        int k = kc * 4;
        float4 xv[4];
        #pragma unroll
        for (int j = 0; j < 4; ++j) xv[j] = *(const float4*)&xs[wg*4 + j][k];
        #pragma unroll
        for (int i = 0; i < 8; ++i) {
            int r = slice*512 + rg*8 + i;
            float4 wv = *(const float4*)(Wih2 + (size_t)r*XDIM + k);
            #pragma unroll
            for (int j = 0; j < 4; ++j)
                acc[i][j] += wv.x*xv[j].x + wv.y*xv[j].y + wv.z*xv[j].z + wv.w*xv[j].w;
        }
    }
    #pragma unroll
    for (int i = 0; i < 8; ++i) {
        int r = slice*512 + rg*8 + i;
        float b = bih2[r] + bhh2[r];
        #pragma unroll
        for (int j = 0; j < 4; ++j)
            Gx[(size_t)(w0 + wg*4 + j)*GW + r] = acc[i][j] + b;
    }
}

// ---------------------------------------------------------------------------
// K3: sequential word LSTM, data-as-flag, batched bypass loads.
// 64 blocks x 256 threads. Block b owns outputs hb..hb+7 (hb=b*8).
// Wave w serves outputs jo = hb + w*2 + (lane&1); lane's k-slice is
// s = lane>>1 (16 k each). Whh2 slice (4 gates x 16 = 64 floats) in VGPRs.
// Step t: poll hext row t with 4x global_load_dwordx4 sc0 sc1 + one
// s_waitcnt (ONE MALL round trip, not 32 serialized atomics), check all 16
// values > 0.5 (stored as h+2), matvec, 5-stage butterfly over s, gates in
// lanes s==0, store row t+1 bypassing caches. Rows write-once => no fences.
// ---------------------------------------------------------------------------
__global__ __launch_bounds__(256, 1) void k_word_lstm(
    const float* __restrict__ Gx, const float* __restrict__ Whh2,
    const float* __restrict__ cx0, float* __restrict__ hext)
{
    const int tid  = threadIdx.x;
    const int b    = blockIdx.x;
    const int hb   = b * 8;
    const int w    = tid >> 6;        // wave 0..3
    const int lane = tid & 63;
    const int jj   = lane & 1;
    const int s    = lane >> 1;       // 0..31
    const int ks   = s * 16;
    const int jo   = hb + w*2 + jj;   // output index this lane serves

    // Whh2 slice -> VGPRs: rows q*HD + jo, cols ks..ks+15; wsum = 2*sum
    float wreg[4][16];
    float wsum[4];
    #pragma unroll
    for (int q = 0; q < 4; ++q) {
        const float* wr = Whh2 + (size_t)(q*HD + jo)*HD + ks;
        float ssum = 0.0f;
        #pragma unroll
        for (int m4 = 0; m4 < 4; ++m4) {
            float4 v = *(const float4*)(wr + m4*4);
            wreg[q][m4*4+0] = v.x; wreg[q][m4*4+1] = v.y;
            wreg[q][m4*4+2] = v.z; wreg[q][m4*4+3] = v.w;
            ssum += v.x + v.y + v.z + v.w;
        }
        wsum[q] = 2.0f * ssum;
    }
    float creg = (s == 0) ? cx0[jo] : 0.0f;

    for (int t = 0; t < S_LEN; ++t) {
        // Gx prefetch (cached loads; overlap the poll)
        float gx0 = 0.f, gx1 = 0.f, gx2 = 0.f, gx3 = 0.f;
        if (s == 0) {
            const float* gp = Gx + (size_t)t*GW + jo;
            gx0 = gp[0]; gx1 = gp[HD]; gx2 = gp[2*HD]; gx3 = gp[3*HD];
        }

        const float* hsrc = hext + (size_t)t*HD + ks;
        v4f r0, r1, r2, r3;
        for (;;) {
            // 4 wide bypass loads + one wait: one pipelined MALL round trip
            asm volatile(
                "global_load_dwordx4 %0, %4, off sc0 sc1\n\t"
                "global_load_dwordx4 %1, %4, off offset:16 sc0 sc1\n\t"
                "global_load_dwordx4 %2, %4, off offset:32 sc0 sc1\n\t"
                "global_load_dwordx4 %3, %4, off offset:48 sc0 sc1\n\t"
                "s_waitcnt vmcnt(0)"
                : "=&v"(r0), "=&v"(r1), "=&v"(r2), "=&v"(r3)
                : "v"(hsrc)
                : "memory");
            float mn = fminf(fminf(fminf(r0.x, r0.y), fminf(r0.z, r0.w)),
                             fminf(fminf(r1.x, r1.y), fminf(r1.z, r1.w)));
            mn = fminf(mn, fminf(fminf(fminf(r2.x, r2.y), fminf(r2.z, r2.w)),
                                 fminf(fminf(r3.x, r3.y), fminf(r3.z, r3.w))));
            if (__all(mn > 0.5f)) break;
            __builtin_amdgcn_s_sleep(1);
        }

        float hv[16];
        hv[0]=r0.x; hv[1]=r0.y; hv[2]=r0.z; hv[3]=r0.w;
        hv[4]=r1.x; hv[5]=r1.y; hv[6]=r1.z; hv[7]=r1.w;
        hv[8]=r2.x; hv[9]=r2.y; hv[10]=r2.z; hv[11]=r2.w;
        hv[12]=r3.x; hv[13]=r3.y; hv[14]=r3.z; hv[15]=r3.w;

        // matvec on (h+2); subtract folded 2*sum(w) afterwards
        float a0 = 0.f, a1 = 0.f, a2 = 0.f, a3 = 0.f;
        #pragma unroll
        for (int m = 0; m < 16; ++m) {
            a0 += wreg[0][m] * hv[m];
            a1 += wreg[1][m] * hv[m];
            a2 += wreg[2][m] * hv[m];
            a3 += wreg[3][m] * hv[m];
        }
        a0 -= wsum[0]; a1 -= wsum[1]; a2 -= wsum[2]; a3 -= wsum[3];

        // butterfly over the s bits (lane ^ 2,4,8,16,32)
        #pragma unroll
        for (int off = 2; off < 64; off <<= 1) {
            a0 += __shfl_xor(a0, off, 64);
            a1 += __shfl_xor(a1, off, 64);
            a2 += __shfl_xor(a2, off, 64);
            a3 += __shfl_xor(a3, off, 64);
        }

        if (s == 0) {
            float g0 = gx0 + a0, g1 = gx1 + a1, g2 = gx2 + a2, g3 = gx3 + a3;
            float c  = sigf(g1)*creg + sigf(g0)*tanhfast(g2);
            creg = c;
            float hn = sigf(g3)*tanhfast(c) + 2.0f;
            float* dst = hext + (size_t)(t+1)*HD + jo;
            asm volatile("global_store_dword %0, %1, off sc0 sc1"
                         :: "v"(dst), "v"(hn) : "memory");
        }
    }
}

// ---------------------------------------------------------------------------
// K4: tag projection + log_softmax. Reads hext rows 1..S_LEN (+2 bias).
// ---------------------------------------------------------------------------
__global__ __launch_bounds__(256) void k_out(
    const float* __restrict__ outs_b, const float* __restrict__ W_out,
    const float* __restrict__ b_out, float* __restrict__ out)
{
    __shared__ float hh[16][HD + 4];
    __shared__ float ts[16][TAGS + 4];
    __shared__ float lse[16];
    const int tid = threadIdx.x;
    const int w0  = blockIdx.x * 16;

    {
        int w = tid >> 4, k0 = (tid & 15) * 32;
        #pragma unroll
        for (int i4 = 0; i4 < 8; ++i4) {
            float4 v = *(const float4*)(outs_b + (size_t)(w0+w)*HD + k0 + i4*4);
            int k = k0 + i4*4;
            hh[w][k+0] = v.x - 2.0f; hh[w][k+1] = v.y - 2.0f;
            hh[w][k+2] = v.z - 2.0f; hh[w][k+3] = v.w - 2.0f;
        }
    }
    __syncthreads();

    const int tag = tid & 63;
    const int wg  = tid >> 6;
    float a0 = 0.f, a1 = 0.f, a2 = 0.f, a3 = 0.f;
    for (int kc = 0; kc < HD/4; ++kc) {
        int k = kc * 4;
        float4 wv = *(const float4*)(W_out + (size_t)tag*HD + k);
        float4 x0 = *(const float4*)&hh[wg*4+0][k];
        float4 x1 = *(const float4*)&hh[wg*4+1][k];
        float4 x2 = *(const float4*)&hh[wg*4+2][k];
        float4 x3 = *(const float4*)&hh[wg*4+3][k];
        a0 += wv.x*x0.x + wv.y*x0.y + wv.z*x0.z + wv.w*x0.w;
        a1 += wv.x*x1.x + wv.y*x1.y + wv.z*x1.z + wv.w*x1.w;
        a2 += wv.x*x2.x + wv.y*x2.y + wv.z*x2.z + wv.w*x2.w;
        a3 += wv.x*x3.x + wv.y*x3.y + wv.z*x3.z + wv.w*x3.w;
    }
    float bo = b_out[tag];
    ts[wg*4+0][tag] = a0 + bo;
    ts[wg*4+1][tag] = a1 + bo;
    ts[wg*4+2][tag] = a2 + bo;
    ts[wg*4+3][tag] = a3 + bo;
    __syncthreads();

    if (tid < 16) {
        float m = -1e30f;
        for (int q = 0; q < TAGS; ++q) m = fmaxf(m, ts[tid][q]);
        float ssum = 0.0f;
        for (int q = 0; q < TAGS; ++q) ssum += __expf(ts[tid][q] - m);
        lse[tid] = m + __logf(ssum);
    }
    __syncthreads();

    #pragma unroll
    for (int jjj = 0; jjj < 4; ++jjj)
        out[(size_t)(w0 + wg*4 + jjj)*TAGS + tag] = ts[wg*4+jjj][tag] - lse[wg*4+jjj];
}

// ---------------------------------------------------------------------------
extern "C" void kernel_launch(void* const* d_in, const int* in_sizes, int n_in,
                              void* d_out, int out_size, void* d_ws, size_t ws_size,
                              hipStream_t stream) {
    (void)in_sizes; (void)n_in; (void)out_size; (void)ws_size;
    const int*   w_seq    = (const int*)  d_in[0];
    const int*   c_seq    = (const int*)  d_in[1];
    const float* char_emb = (const float*)d_in[2];
    const float* word_emb = (const float*)d_in[3];
    const float* c_hx0    = (const float*)d_in[4];
    const float* c_cx0    = (const float*)d_in[5];
    const float* hx0      = (const float*)d_in[6];
    const float* cx0      = (const float*)d_in[7];
    const float* Wih1     = (const float*)d_in[8];
    const float* Whh1     = (const float*)d_in[9];
    const float* bih1     = (const float*)d_in[10];
    const float* bhh1     = (const float*)d_in[11];
    const float* Wih2     = (const float*)d_in[12];
    const float* Whh2     = (const float*)d_in[13];
    const float* bih2     = (const float*)d_in[14];
    const float* bhh2     = (const float*)d_in[15];
    const float* W_out    = (const float*)d_in[16];
    const float* b_out    = (const float*)d_in[17];

    float* ws   = (float*)d_ws;
    float* Gx   = ws + WS_GX;
    float* crep = ws + WS_CREP;
    float* hext = ws + WS_HEXT;

    int init_blocks = (int)(((size_t)(S_LEN + 1) * HD / 4 + 255) / 256);
    hipLaunchKernelGGL(k_init, dim3(init_blocks), dim3(256), 0, stream, hx0, hext);
    hipLaunchKernelGGL(k_char_lstm, dim3(256), dim3(256), 0, stream,
                       c_seq, char_emb, c_hx0, c_cx0, Wih1, Whh1, bih1, bhh1, crep);
    hipLaunchKernelGGL(k_gx, dim3(256, 4), dim3(256), 0, stream,
                       w_seq, word_emb, crep, Wih2, bih2, bhh2, Gx);
    hipLaunchKernelGGL(k_word_lstm, dim3(NBLK), dim3(256), 0, stream,
                       Gx, Whh2, cx0, hext);
    hipLaunchKernelGGL(k_out, dim3(256), dim3(256), 0, stream,
                       hext + HD, W_out, b_out, (float*)d_out);
}

// Round 4
// 10555.041 us; speedup vs baseline: 2.1989x; 1.0074x over previous
//
#include <hip/hip_runtime.h>
#include <math.h>

#define S_LEN 4096
#define L_CH  12
#define CE    64
#define CHD   128
#define WE    256
#define HD    512
#define TAGS  64
#define GW    (4*HD)      // 2048
#define XDIM  (CHD+WE)    // 384
#define NBLK  128         // word-LSTM blocks (4 outputs each, 1 per wave)

// ws layout (float offsets)
#define WS_GX    0
#define WS_CREP  (WS_GX   + (size_t)S_LEN*GW)      // 8,388,608 floats
#define WS_HEXT  (WS_CREP + (size_t)S_LEN*CHD)     // +524,288
// hext: (S_LEN+1) rows x HD. Row r = h_{r-1} + 2.0 (row 0 = hx0+2).
// Rows 1..S_LEN double as `outs` (+2 bias) for k_out.

typedef float v4f __attribute__((ext_vector_type(4)));

static __device__ __forceinline__ float sigf(float x) {
    return 1.0f / (1.0f + __expf(-x));
}
static __device__ __forceinline__ float tanhfast(float x) {
    return 1.0f - 2.0f / (__expf(2.0f * x) + 1.0f);
}
static __device__ __forceinline__ float dot4(v4f a, v4f b) {
    return a.x*b.x + a.y*b.y + a.z*b.z + a.w*b.w;
}
// DPP-assisted partial-sum step: a += dpp_move(a). Masked-off rows add 0.
template <int CTRL, int RMASK>
static __device__ __forceinline__ float dpp_add(float a) {
    int t = __builtin_amdgcn_update_dpp(0, __float_as_int(a), CTRL, RMASK, 0xf, true);
    return a + __int_as_float(t);
}
static __device__ __forceinline__ float rdlane(float v, int l) {
    return __int_as_float(__builtin_amdgcn_readlane(__float_as_int(v), l));
}

// ---------------------------------------------------------------------------
// K_init: hext row 0 = hx0 + 2, rows 1..S_LEN = 0, stores bypassing L1/L2
// (sc0 sc1) so readiness state lives at MALL from the start.
// ---------------------------------------------------------------------------
__global__ __launch_bounds__(256) void k_init(const float* __restrict__ hx0,
                                              float* __restrict__ hext) {
    size_t i = ((size_t)blockIdx.x * 256 + threadIdx.x) * 4;
    if (i >= (size_t)(S_LEN + 1) * HD) return;
    v4f v;
    if (i < HD) {
        v.x = hx0[i+0] + 2.0f; v.y = hx0[i+1] + 2.0f;
        v.z = hx0[i+2] + 2.0f; v.w = hx0[i+3] + 2.0f;
    } else {
        v.x = 0.f; v.y = 0.f; v.z = 0.f; v.w = 0.f;
    }
    float* p = hext + i;
    asm volatile("global_store_dwordx4 %0, %1, off sc0 sc1"
                 :: "v"(p), "v"(v) : "memory");
}

// ---------------------------------------------------------------------------
// K1: char LSTM. 256 blocks x 256 threads; block owns 16 words, runs 12 steps.
// ---------------------------------------------------------------------------
__global__ __launch_bounds__(256) void k_char_lstm(
    const int* __restrict__ c_seq, const float* __restrict__ char_emb,
    const float* __restrict__ c_hx0, const float* __restrict__ c_cx0,
    const float* __restrict__ Wih1, const float* __restrict__ Whh1,
    const float* __restrict__ bih1, const float* __restrict__ bhh1,
    float* __restrict__ char_rep)
{
    __shared__ float xs[16][CE + 4];
    __shared__ float hs[16][CHD + 4];
    __shared__ float cs[16][CHD + 4];
    __shared__ float gs[16][4*CHD + 4];
    const int tid = threadIdx.x;
    const int w0  = blockIdx.x * 16;

    for (int u = tid; u < 16*CHD; u += 256) {
        int w = u >> 7, k = u & (CHD-1);
        hs[w][k] = c_hx0[k];
        cs[w][k] = c_cx0[k];
    }
    __syncthreads();

    const int wg = tid & 3;
    const int rg = tid >> 2;
    const int uw = tid >> 4;
    const int uj = (tid & 15) * 8;

    for (int t = 0; t < L_CH; ++t) {
        {
            int w = tid >> 4, k4 = (tid & 15) * 4;
            int ci = c_seq[(w0 + w) * L_CH + t];
            float4 v = *(const float4*)(char_emb + (size_t)ci * CE + k4);
            *(float4*)&xs[w][k4] = v;
        }
        __syncthreads();

        float acc[8][4];
        #pragma unroll
        for (int i = 0; i < 8; ++i)
            #pragma unroll
            for (int j = 0; j < 4; ++j) acc[i][j] = 0.0f;

        for (int kc = 0; kc < CE/4; ++kc) {
            int k = kc * 4;
            float4 xv[4];
            #pragma unroll
            for (int j = 0; j < 4; ++j) xv[j] = *(const float4*)&xs[wg*4 + j][k];
            #pragma unroll
            for (int i = 0; i < 8; ++i) {
                int r = rg*8 + i;
                float4 wv = *(const float4*)(Wih1 + (size_t)r*CE + k);
                #pragma unroll
                for (int j = 0; j < 4; ++j)
                    acc[i][j] += wv.x*xv[j].x + wv.y*xv[j].y + wv.z*xv[j].z + wv.w*xv[j].w;
            }
        }
        for (int kc = 0; kc < CHD/4; ++kc) {
            int k = kc * 4;
            float4 hv[4];
            #pragma unroll
            for (int j = 0; j < 4; ++j) hv[j] = *(const float4*)&hs[wg*4 + j][k];
            #pragma unroll
            for (int i = 0; i < 8; ++i) {
                int r = rg*8 + i;
                float4 wv = *(const float4*)(Whh1 + (size_t)r*CHD + k);
                #pragma unroll
                for (int j = 0; j < 4; ++j)
                    acc[i][j] += wv.x*hv[j].x + wv.y*hv[j].y + wv.z*hv[j].z + wv.w*hv[j].w;
            }
        }
        #pragma unroll
        for (int i = 0; i < 8; ++i) {
            int r = rg*8 + i;
            float b = bih1[r] + bhh1[r];
            #pragma unroll
            for (int j = 0; j < 4; ++j) gs[wg*4 + j][r] = acc[i][j] + b;
        }
        __syncthreads();

        #pragma unroll
        for (int i = 0; i < 8; ++i) {
            int j = uj + i;
            float gi = gs[uw][j];
            float gf = gs[uw][CHD + j];
            float gg = gs[uw][2*CHD + j];
            float go = gs[uw][3*CHD + j];
            float c = sigf(gf)*cs[uw][j] + sigf(gi)*tanhfast(gg);
            cs[uw][j] = c;
            hs[uw][j] = sigf(go)*tanhfast(c);
        }
        __syncthreads();
    }
    #pragma unroll
    for (int i4 = 0; i4 < 2; ++i4) {
        float4 v;
        v.x = hs[uw][uj + i4*4 + 0]; v.y = hs[uw][uj + i4*4 + 1];
        v.z = hs[uw][uj + i4*4 + 2]; v.w = hs[uw][uj + i4*4 + 3];
        *(float4*)(char_rep + (size_t)(w0 + uw)*CHD + uj + i4*4) = v;
    }
}

// ---------------------------------------------------------------------------
// K2: Gx[t][2048] = concat(char_rep, wv)[t] @ Wih2^T + (bih2+bhh2)
// ---------------------------------------------------------------------------
__global__ __launch_bounds__(256) void k_gx(
    const int* __restrict__ w_seq, const float* __restrict__ word_emb,
    const float* __restrict__ char_rep,
    const float* __restrict__ Wih2, const float* __restrict__ bih2,
    const float* __restrict__ bhh2, float* __restrict__ Gx)
{
    __shared__ float xs[16][XDIM + 4];
    const int tid = threadIdx.x;
    const int w0  = blockIdx.x * 16;
    const int slice = blockIdx.y;

    {
        int w = tid >> 4, seg = tid & 15;
        int wsq = w_seq[w0 + w];
        #pragma unroll
        for (int i4 = 0; i4 < 6; ++i4) {
            int k = seg*24 + i4*4;
            float4 v;
            if (k < CHD) v = *(const float4*)(char_rep + (size_t)(w0+w)*CHD + k);
            else         v = *(const float4*)(word_emb + (size_t)wsq*WE + (k - CHD));
            *(float4*)&xs[w][k] = v;
        }
    }
    __syncthreads();

    const int wg = tid & 3, rg = tid >> 2;
    float acc[8][4];
    #pragma unroll
    for (int i = 0; i < 8; ++i)
        #pragma unroll
        for (int j = 0; j < 4; ++j) acc[i][j] = 0.0f;

    for (int kc = 0; kc < XDIM/4; ++kc) {
        int k = kc * 4;
        float4 xv[4];
        #pragma unroll
        for (int j = 0; j < 4; ++j) xv[j] = *(const float4*)&xs[wg*4 + j][k];
        #pragma unroll
        for (int i = 0; i < 8; ++i) {
            int r = slice*512 + rg*8 + i;
            float4 wv = *(const float4*)(Wih2 + (size_t)r*XDIM + k);
            #pragma unroll
            for (int j = 0; j < 4; ++j)
                acc[i][j] += wv.x*xv[j].x + wv.y*xv[j].y + wv.z*xv[j].z + wv.w*xv[j].w;
        }
    }
    #pragma unroll
    for (int i = 0; i < 8; ++i) {
        int r = slice*512 + rg*8 + i;
        float b = bih2[r] + bhh2[r];
        #pragma unroll
        for (int j = 0; j < 4; ++j)
            Gx[(size_t)(w0 + wg*4 + j)*GW + r] = acc[i][j] + b;
    }
}

// ---------------------------------------------------------------------------
// K3: sequential word LSTM, data-as-flag, remat-proof weights + DPP reduce.
// 128 blocks x 256 threads. Wave w of block b owns output jo = b*4 + w.
// Lane: gate-pair g2 = lane>>5 (gates 2*g2, 2*g2+1), k-slice kk=(lane&31)*16.
// Weights (2 gates x 16 = 32 floats) loaded via asm volatile -> cannot be
// rematerialized into the loop; low pressure -> stays in VGPRs.
// Step t: poll hext row t (4x dwordx4 sc0 sc1, one MALL round trip; ready iff
// all 16 values > 0.5, stored as h+2), matvec (2 gates x 16 FMA), 32-lane DPP
// row-reduce (row_shr 1/2/4/8 + row_bcast15), 4x readlane -> wave-uniform gate
// sums, all lanes compute gates redundantly (no divergence), lane 0 stores
// h_{t+1}+2 bypassing caches. Write-once rows => no fences needed.
// ---------------------------------------------------------------------------
__global__ __launch_bounds__(256, 1) void k_word_lstm(
    const float* __restrict__ Gx, const float* __restrict__ Whh2,
    const float* __restrict__ cx0, float* __restrict__ hext)
{
    const int tid  = threadIdx.x;
    const int w    = tid >> 6;         // wave 0..3
    const int lane = tid & 63;
    const int jo   = blockIdx.x * 4 + w;   // output this wave serves (0..511)
    const int g2   = lane >> 5;        // gate pair: gates 2*g2, 2*g2+1
    const int qe   = g2 * 2, qo = qe + 1;
    const int kk   = (lane & 31) * 16; // k-slice of 16

    // weights via asm volatile (opaque to remat). 2 gates x 4 v4f.
    v4f we0, we1, we2, we3, wo0, wo1, wo2, wo3;
    {
        const float* wre = Whh2 + (size_t)(qe*HD + jo)*HD + kk;
        const float* wro = Whh2 + (size_t)(qo*HD + jo)*HD + kk;
        asm volatile(
            "global_load_dwordx4 %0, %8, off\n\t"
            "global_load_dwordx4 %1, %8, off offset:16\n\t"
            "global_load_dwordx4 %2, %8, off offset:32\n\t"
            "global_load_dwordx4 %3, %8, off offset:48\n\t"
            "global_load_dwordx4 %4, %9, off\n\t"
            "global_load_dwordx4 %5, %9, off offset:16\n\t"
            "global_load_dwordx4 %6, %9, off offset:32\n\t"
            "global_load_dwordx4 %7, %9, off offset:48\n\t"
            "s_waitcnt vmcnt(0)"
            : "=&v"(we0), "=&v"(we1), "=&v"(we2), "=&v"(we3),
              "=&v"(wo0), "=&v"(wo1), "=&v"(wo2), "=&v"(wo3)
            : "v"(wre), "v"(wro));
    }
    const float wsum_e = 2.0f * (we0.x+we0.y+we0.z+we0.w + we1.x+we1.y+we1.z+we1.w
                               + we2.x+we2.y+we2.z+we2.w + we3.x+we3.y+we3.z+we3.w);
    const float wsum_o = 2.0f * (wo0.x+wo0.y+wo0.z+wo0.w + wo1.x+wo1.y+wo1.z+wo1.w
                               + wo2.x+wo2.y+wo2.z+wo2.w + wo3.x+wo3.y+wo3.z+wo3.w);
    float creg = cx0[jo];              // uniform across the wave

    for (int t = 0; t < S_LEN; ++t) {
        // Gx prefetch: all lanes load the same 4 addresses (wave-broadcast),
        // issued before the poll so latency overlaps it.
        const float* gp = Gx + (size_t)t*GW + jo;
        float gx0 = gp[0], gx1 = gp[HD], gx2 = gp[2*HD], gx3 = gp[3*HD];

        const float* hsrc = hext + (size_t)t*HD + kk;
        v4f r0, r1, r2, r3;
        for (;;) {
            asm volatile(
                "global_load_dwordx4 %0, %4, off sc0 sc1\n\t"
                "global_load_dwordx4 %1, %4, off offset:16 sc0 sc1\n\t"
                "global_load_dwordx4 %2, %4, off offset:32 sc0 sc1\n\t"
                "global_load_dwordx4 %3, %4, off offset:48 sc0 sc1\n\t"
                "s_waitcnt vmcnt(0)"
                : "=&v"(r0), "=&v"(r1), "=&v"(r2), "=&v"(r3)
                : "v"(hsrc)
                : "memory");
            float mn = fminf(fminf(fminf(r0.x, r0.y), fminf(r0.z, r0.w)),
                             fminf(fminf(r1.x, r1.y), fminf(r1.z, r1.w)));
            mn = fminf(mn, fminf(fminf(fminf(r2.x, r2.y), fminf(r2.z, r2.w)),
                                 fminf(fminf(r3.x, r3.y), fminf(r3.z, r3.w))));
            if (__all(mn > 0.5f)) break;
        }

        // matvec on (h+2), fold out the +2 via wsum
        float ae = dot4(we0, r0) + dot4(we1, r1) + dot4(we2, r2) + dot4(we3, r3) - wsum_e;
        float ao = dot4(wo0, r0) + dot4(wo1, r1) + dot4(wo2, r2) + dot4(wo3, r3) - wsum_o;

        // 32-lane DPP reduce: lane31 = sum(lanes 0..31), lane63 = sum(32..63)
        ae = dpp_add<0x111, 0xf>(ae); ao = dpp_add<0x111, 0xf>(ao);
        ae = dpp_add<0x112, 0xf>(ae); ao = dpp_add<0x112, 0xf>(ao);
        ae = dpp_add<0x114, 0xf>(ae); ao = dpp_add<0x114, 0xf>(ao);
        ae = dpp_add<0x118, 0xf>(ae); ao = dpp_add<0x118, 0xf>(ao);
        ae = dpp_add<0x142, 0xa>(ae); ao = dpp_add<0x142, 0xa>(ao);

        // gate sums, wave-uniform (i,f from group0; g,o from group1)
        float si = rdlane(ae, 31), sf = rdlane(ao, 31);
        float sg = rdlane(ae, 63), so = rdlane(ao, 63);

        float g0 = gx0 + si, g1 = gx1 + sf, g2v = gx2 + sg, g3 = gx3 + so;
        float c  = sigf(g1)*creg + sigf(g0)*tanhfast(g2v);
        creg = c;
        float hn = sigf(g3)*tanhfast(c) + 2.0f;
        if (lane == 0) {
            float* dst = hext + (size_t)(t+1)*HD + jo;
            asm volatile("global_store_dword %0, %1, off sc0 sc1"
                         :: "v"(dst), "v"(hn) : "memory");
        }
    }
}

// ---------------------------------------------------------------------------
// K4: tag projection + log_softmax. Reads hext rows 1..S_LEN (+2 bias).
// ---------------------------------------------------------------------------
__global__ __launch_bounds__(256) void k_out(
    const float* __restrict__ outs_b, const float* __restrict__ W_out,
    const float* __restrict__ b_out, float* __restrict__ out)
{
    __shared__ float hh[16][HD + 4];
    __shared__ float ts[16][TAGS + 4];
    __shared__ float lse[16];
    const int tid = threadIdx.x;
    const int w0  = blockIdx.x * 16;

    {
        int w = tid >> 4, k0 = (tid & 15) * 32;
        #pragma unroll
        for (int i4 = 0; i4 < 8; ++i4) {
            float4 v = *(const float4*)(outs_b + (size_t)(w0+w)*HD + k0 + i4*4);
            int k = k0 + i4*4;
            hh[w][k+0] = v.x - 2.0f; hh[w][k+1] = v.y - 2.0f;
            hh[w][k+2] = v.z - 2.0f; hh[w][k+3] = v.w - 2.0f;
        }
    }
    __syncthreads();

    const int tag = tid & 63;
    const int wg  = tid >> 6;
    float a0 = 0.f, a1 = 0.f, a2 = 0.f, a3 = 0.f;
    for (int kc = 0; kc < HD/4; ++kc) {
        int k = kc * 4;
        float4 wv = *(const float4*)(W_out + (size_t)tag*HD + k);
        float4 x0 = *(const float4*)&hh[wg*4+0][k];
        float4 x1 = *(const float4*)&hh[wg*4+1][k];
        float4 x2 = *(const float4*)&hh[wg*4+2][k];
        float4 x3 = *(const float4*)&hh[wg*4+3][k];
        a0 += wv.x*x0.x + wv.y*x0.y + wv.z*x0.z + wv.w*x0.w;
        a1 += wv.x*x1.x + wv.y*x1.y + wv.z*x1.z + wv.w*x1.w;
        a2 += wv.x*x2.x + wv.y*x2.y + wv.z*x2.z + wv.w*x2.w;
        a3 += wv.x*x3.x + wv.y*x3.y + wv.z*x3.z + wv.w*x3.w;
    }
    float bo = b_out[tag];
    ts[wg*4+0][tag] = a0 + bo;
    ts[wg*4+1][tag] = a1 + bo;
    ts[wg*4+2][tag] = a2 + bo;
    ts[wg*4+3][tag] = a3 + bo;
    __syncthreads();

    if (tid < 16) {
        float m = -1e30f;
        for (int q = 0; q < TAGS; ++q) m = fmaxf(m, ts[tid][q]);
        float ssum = 0.0f;
        for (int q = 0; q < TAGS; ++q) ssum += __expf(ts[tid][q] - m);
        lse[tid] = m + __logf(ssum);
    }
    __syncthreads();

    #pragma unroll
    for (int jjj = 0; jjj < 4; ++jjj)
        out[(size_t)(w0 + wg*4 + jjj)*TAGS + tag] = ts[wg*4+jjj][tag] - lse[wg*4+jjj];
}

// ---------------------------------------------------------------------------
extern "C" void kernel_launch(void* const* d_in, const int* in_sizes, int n_in,
                              void* d_out, int out_size, void* d_ws, size_t ws_size,
                              hipStream_t stream) {
    (void)in_sizes; (void)n_in; (void)out_size; (void)ws_size;
    const int*   w_seq    = (const int*)  d_in[0];
    const int*   c_seq    = (const int*)  d_in[1];
    const float* char_emb = (const float*)d_in[2];
    const float* word_emb = (const float*)d_in[3];
    const float* c_hx0    = (const float*)d_in[4];
    const float* c_cx0    = (const float*)d_in[5];
    const float* hx0      = (const float*)d_in[6];
    const float* cx0      = (const float*)d_in[7];
    const float* Wih1     = (const float*)d_in[8];
    const float* Whh1     = (const float*)d_in[9];
    const float* bih1     = (const float*)d_in[10];
    const float* bhh1     = (const float*)d_in[11];
    const float* Wih2     = (const float*)d_in[12];
    const float* Whh2     = (const float*)d_in[13];
    const float* bih2     = (const float*)d_in[14];
    const float* bhh2     = (const float*)d_in[15];
    const float* W_out    = (const float*)d_in[16];
    const float* b_out    = (const float*)d_in[17];

    float* ws   = (float*)d_ws;
    float* Gx   = ws + WS_GX;
    float* crep = ws + WS_CREP;
    float* hext = ws + WS_HEXT;

    int init_blocks = (int)(((size_t)(S_LEN + 1) * HD / 4 + 255) / 256);
    hipLaunchKernelGGL(k_init, dim3(init_blocks), dim3(256), 0, stream, hx0, hext);
    hipLaunchKernelGGL(k_char_lstm, dim3(256), dim3(256), 0, stream,
                       c_seq, char_emb, c_hx0, c_cx0, Wih1, Whh1, bih1, bhh1, crep);
    hipLaunchKernelGGL(k_gx, dim3(256, 4), dim3(256), 0, stream,
                       w_seq, word_emb, crep, Wih2, bih2, bhh2, Gx);
    hipLaunchKernelGGL(k_word_lstm, dim3(NBLK), dim3(256), 0, stream,
                       Gx, Whh2, cx0, hext);
    hipLaunchKernelGGL(k_out, dim3(256), dim3(256), 0, stream,
                       hext + HD, W_out, b_out, (float*)d_out);
}